// Round 9
// baseline (235.581 us; speedup 1.0000x reference)
//
#include <hip/hip_runtime.h>

// TrainablePCEN: x[B=64,F=128,T=4000] f32; EMA along T then pointwise ops.
// R6 post-mortem: both barrier-based structures stuck at 78us with nothing
// saturated -> barrier vmcnt(0) drains + phase-bursty memory. This version:
// one WAVE per row, zero __syncthreads (wave-private LDS slice, lgkmcnt only),
// stride-17 LDS transpose for coalescing (2-way bank alias = free), uniform-
// multiplier scan (A const => scan only B: 6 shfl), chunk-ahead load prefetch.

#define EXP2F(v) __builtin_amdgcn_exp2f(v)
#define LOG2F(v) __builtin_amdgcn_logf(v)
#define RCPF(v)  __builtin_amdgcn_rcpf(v)

constexpr int   T_LEN = 4000;
constexpr int   F_DIM = 128;
constexpr int   TPB   = 256;            // 4 waves, one row per wave
constexpr int   RPB   = 4;              // rows per block
constexpr float S_C   = 0.025f;
constexpr float A1    = 0.975f;
constexpr float EPS_C = 1e-6f;
constexpr int   LROW  = 17;             // padded LDS row stride (floats)
constexpr int   WSLICE = 64 * LROW;     // floats per wave slice

constexpr double dpow(double a, int n){ double r = 1; for (int i = 0; i < n; ++i) r *= a; return r; }
constexpr float K1  = (float)dpow(0.975, 16);
constexpr float K2  = (float)dpow(0.975, 32);
constexpr float K4  = (float)dpow(0.975, 64);
constexpr float K8  = (float)dpow(0.975, 128);
constexpr float K16 = (float)dpow(0.975, 256);
constexpr float K32 = (float)dpow(0.975, 512);
constexpr float C16 = -0.5844128f;      // 16*log2(0.975)

struct RowParams { float g, b, p, bp; bool fast; };

template<int NF4>
__device__ __forceinline__ void load_chunk(const float4* xr4, int c, int lane, float4 B[4]) {
    #pragma unroll
    for (int r = 0; r < 4; ++r) {
        const int i4 = r * 64 + lane;
        if (NF4 == 256 || i4 < NF4) B[r] = xr4[c * 256 + i4];
        else                        B[r] = make_float4(0.f, 0.f, 0.f, 0.f);
    }
}

__device__ __forceinline__ void stage_chunk(float* L, int tw, const float4 B[4]) {
    #pragma unroll
    for (int r = 0; r < 4; ++r) {
        float* d = L + r * (16 * LROW) + tw;
        d[0] = B[r].x; d[1] = B[r].y; d[2] = B[r].z; d[3] = B[r].w;
    }
}

template<int NF4, bool FIRST, bool LAST>
__device__ __forceinline__ void compute_chunk(float* L, float4* qr4, int c,
    int lane, int tr, int tw, float& m0, const RowParams& rp)
{
    // each lane takes its 16 contiguous elems (2-way bank alias: free)
    float xl[16];
    #pragma unroll
    for (int j = 0; j < 16; ++j) xl[j] = L[tr + j];

    if (FIRST) m0 = __shfl(xl[0], 0);          // m_{-1} = x[0]

    // per-lane affine offset over its 16 elems (multiplier uniform = 0.975^16)
    float Bv = S_C * xl[0];
    #pragma unroll
    for (int j = 1; j < 16; ++j) Bv = fmaf(A1, Bv, S_C * xl[j]);

    // Kogge-Stone scan of B with compile-time constant multipliers
    float t;
    t = __shfl_up(Bv,  1);  Bv = (lane >=  1) ? fmaf(K1 , t, Bv) : Bv;
    t = __shfl_up(Bv,  2);  Bv = (lane >=  2) ? fmaf(K2 , t, Bv) : Bv;
    t = __shfl_up(Bv,  4);  Bv = (lane >=  4) ? fmaf(K4 , t, Bv) : Bv;
    t = __shfl_up(Bv,  8);  Bv = (lane >=  8) ? fmaf(K8 , t, Bv) : Bv;
    t = __shfl_up(Bv, 16);  Bv = (lane >= 16) ? fmaf(K16, t, Bv) : Bv;
    t = __shfl_up(Bv, 32);  Bv = (lane >= 32) ? fmaf(K32, t, Bv) : Bv;

    float E = __shfl_up(Bv, 1);
    if (lane == 0) E = 0.f;

    // m entering this lane's 16-elem segment
    float m = fmaf(EXP2F(C16 * (float)lane), m0, E);

    if (rp.fast) {                              // g=b=p=1: out = x / (m+eps)
        #pragma unroll
        for (int j = 0; j < 16; ++j) {
            m = fmaf(A1, m, S_C * xl[j]);
            xl[j] = xl[j] * RCPF(m + EPS_C);
        }
    } else {
        #pragma unroll
        for (int j = 0; j < 16; ++j) {
            m = fmaf(A1, m, S_C * xl[j]);
            float v = xl[j] * EXP2F(-rp.g * LOG2F(m + EPS_C));  // x/(m+eps)^g
            xl[j] = EXP2F(rp.p * LOG2F(v + rp.b)) - rp.bp;      // (v+b)^p - b^p
        }
    }

    if (!LAST) m0 = __shfl(m, 63);              // exact carry (chunk fully real)

    // transpose back through own LDS row, then coalesced float4 stores
    #pragma unroll
    for (int j = 0; j < 16; ++j) L[tr + j] = xl[j];

    #pragma unroll
    for (int r = 0; r < 4; ++r) {
        const int i4 = r * 64 + lane;
        if (NF4 == 256 || i4 < NF4) {
            const float* s = L + r * (16 * LROW) + tw;
            qr4[c * 256 + i4] = make_float4(s[0], s[1], s[2], s[3]);
        }
    }
}

__global__ __launch_bounds__(TPB) void pcen_kernel(
    const float* __restrict__ x,
    const float* __restrict__ log_gain,
    const float* __restrict__ log_bias,
    const float* __restrict__ log_power,
    float* __restrict__ out)
{
    const int tid  = threadIdx.x;
    const int lane = tid & 63;
    const int wid  = tid >> 6;
    const int row  = blockIdx.x * RPB + wid;
    const int f    = row & (F_DIM - 1);

    const float4* xr4 = reinterpret_cast<const float4*>(x + (long long)row * T_LEN);
    float4*       qr4 = reinterpret_cast<float4*>(out + (long long)row * T_LEN);

    RowParams rp;
    rp.g = expf(log_gain[f]);
    rp.b = expf(log_bias[f]);
    rp.p = expf(log_power[f]);
    rp.fast = (rp.g == 1.0f) && (rp.b == 1.0f) && (rp.p == 1.0f);
    rp.bp = EXP2F(rp.p * LOG2F(rp.b));   // same path as output -> x=0 gives exact 0

    __shared__ float lds[RPB * WSLICE];  // 17408 B; wave-private slices, NO barriers
    float* L = lds + wid * WSLICE;
    const int tr = lane * LROW;                          // own-row base
    const int tw = (lane >> 2) * LROW + (lane & 3) * 4;  // transpose base

    float4 b0[4], b1[4];
    float m0 = 0.f;

    // chunks: 1024,1024,1024,928 elems (256,256,256,232 float4; tail zero-padded)
    load_chunk<256>(xr4, 0, lane, b0);
    load_chunk<256>(xr4, 1, lane, b1);

    stage_chunk(L, tw, b0);
    load_chunk<256>(xr4, 2, lane, b0);                   // prefetch overlaps scan
    compute_chunk<256, true , false>(L, qr4, 0, lane, tr, tw, m0, rp);

    stage_chunk(L, tw, b1);
    load_chunk<232>(xr4, 3, lane, b1);
    compute_chunk<256, false, false>(L, qr4, 1, lane, tr, tw, m0, rp);

    stage_chunk(L, tw, b0);
    compute_chunk<256, false, false>(L, qr4, 2, lane, tr, tw, m0, rp);

    stage_chunk(L, tw, b1);
    compute_chunk<232, false, true >(L, qr4, 3, lane, tr, tw, m0, rp);
}

extern "C" void kernel_launch(void* const* d_in, const int* in_sizes, int n_in,
                              void* d_out, int out_size, void* d_ws, size_t ws_size,
                              hipStream_t stream) {
    const float* x  = (const float*)d_in[0];
    const float* lg = (const float*)d_in[1];
    const float* lb = (const float*)d_in[2];
    const float* lp = (const float*)d_in[3];
    float* out = (float*)d_out;

    const int rows = in_sizes[0] / T_LEN;     // B*F = 8192
    pcen_kernel<<<dim3(rows / RPB), dim3(TPB), 0, stream>>>(x, lg, lb, lp, out);
}